// Round 6
// baseline (251.379 us; speedup 1.0000x reference)
//
#include <hip/hip_runtime.h>

// EMA along T for x[B=8, T=4096, F=1024] fp32.
// y_t = a*y_{t-1} + (1-a)*x_t, a=0.9, y_{-1}=0.
//
// Chunked scan with truncated warm-up (W=64; 0.9^64 ~ 1.2e-3 << 2.58e-2).
//
// v7: contiguous block-streams AT 8 WAVES/CU with tight lockstep.
// Evidence: across v1-v6, HBM rate is pinned at 2.4-2.8 TB/s while L1-level
// rates vary 30% -- the limiter is DRAM-side and insensitive to occupancy,
// per-wave MLP, and store type. Copy ubench does 6.3 TB/s with the same
// read:write mix; the difference is shape: our per-wave streams are 1 KiB
// bursts at 4 KiB stride (row-buffer thrash across ~64 interleaved streams
// per XCD). v4 tested contiguity but at 4 waves/CU with a loose 32-KiB
// lockstep window. v7 = block spans the full 4 KiB row (f4i = tid), block
// streams a contiguous region t-sequentially, 512 blocks (2/CU, 8 waves/CU
// like v2), s_barrier every 4 steps (16 KiB drift window) keeps the 4
// waves' row accesses adjacent. nt stores; XCD pinning groups chunks 8-at-
// a-time per XCD so warm-up re-reads stay L2-local (FETCH stays ~input).

using f4 = __attribute__((ext_vector_type(4))) float;

constexpr int Bn = 8;
constexpr int Tn = 4096;
constexpr int F4 = 256;        // 1024 floats / 4
constexpr int L  = 64;         // outputs per thread (64 chunks)
constexpr int W  = 64;         // warm-up steps (0.9^64 ~ 1.18e-3)
constexpr float A   = 0.9f;
constexpr float OMA = 0.1f;    // 1 - alpha

__global__ __launch_bounds__(256) void ema_kernel(const f4* __restrict__ x,
                                                  f4* __restrict__ y) {
    // 512 blocks = 8 xcd x 8 chunk-in-group x 8 b.
    // chunk = xcd*8 + lo: chunks 8k..8k+7 share an XCD, so a chunk's
    // warm-up region (tail of chunk-1's main region) is L2-local for
    // 7 of every 8 chunks.
    const int blk   = blockIdx.x;        // 0..511
    const int xcd   = blk & 7;
    const int r     = blk >> 3;          // 0..63
    const int b     = r >> 3;            // 0..7
    const int chunk = (xcd << 3) | (r & 7);  // 0..63 (block-uniform)
    const int t0    = chunk * L;

    const int f4i = threadIdx.x;         // 0..255: block spans the full 4 KiB row

    const f4* __restrict__ xp = x + (size_t)b * Tn * F4 + f4i;
    f4*       __restrict__ yp = y + (size_t)b * Tn * F4 + f4i;

    float ax = 0.f, ay = 0.f, az = 0.f, aw = 0.f;

    if (chunk > 0) {   // block-uniform branch
        int idx = (t0 - W) * F4;
        #pragma unroll 8
        for (int i = 0; i < W; ++i) {
            f4 v = xp[idx];
            idx += F4;
            ax = fmaf(A, ax, OMA * v.x);
            ay = fmaf(A, ay, OMA * v.y);
            az = fmaf(A, az, OMA * v.z);
            aw = fmaf(A, aw, OMA * v.w);
            if ((i & 3) == 3) __builtin_amdgcn_s_barrier();  // lockstep hint
        }
    }

    int idx = t0 * F4;
    #pragma unroll 8
    for (int i = 0; i < L; ++i) {
        f4 v = xp[idx];
        ax = fmaf(A, ax, OMA * v.x);
        ay = fmaf(A, ay, OMA * v.y);
        az = fmaf(A, az, OMA * v.z);
        aw = fmaf(A, aw, OMA * v.w);
        f4 o;
        o.x = ax; o.y = ay; o.z = az; o.w = aw;
        __builtin_nontemporal_store(o, yp + idx);
        idx += F4;
        if ((i & 3) == 3) __builtin_amdgcn_s_barrier();      // lockstep hint
    }
}

extern "C" void kernel_launch(void* const* d_in, const int* in_sizes, int n_in,
                              void* d_out, int out_size, void* d_ws, size_t ws_size,
                              hipStream_t stream) {
    const f4* x = (const f4*)d_in[0];
    f4*       y = (f4*)d_out;
    dim3 grid(Bn * (Tn / L));   // 512 blocks (8 b x 64 chunks)
    dim3 block(256);
    ema_kernel<<<grid, block, 0, stream>>>(x, y);
}